// Round 4
// baseline (74.710 us; speedup 1.0000x reference)
//
#include <hip/hip_runtime.h>

// Problem: B=16,H=16,P=128,D=128,NF=12
// rows per branch = B*H*P = 32768; total rows (q then k) = 65536.
//
// grid = [1..12] => sin(f*x) by Chebyshev recurrence off sincos(g1*x).
//
// k_branch structure (the R4 fix: no long-lived acc across the epilogue):
//   phase 1: stage silu(x)->A_l bf16, W->W_l bf16 (swizzled)     [48 KB LDS]
//   phase 2: MFMA  out[m][n] = silu(x) @ W^T  -> acc[8] (f32x4)
//   phase 3: barrier; acc -> F_l f32 [64][132] (overlaps dead A/W); barrier
//   phase 4: per-thread row-chunk epilogue, ALL loads vectorized:
//            x/ssp/sbase/coef float4 from global (L1/L2), F via ds_read_b128
//
// ws layout (floats):
//   sums: [0, 65536)   R: [65536, 65664)   T: [65664, 98432)
//   wbf:  [98432, ...) base_weight bf16 bits (16384 ushorts)

typedef float          f32x4 __attribute__((ext_vector_type(4)));
typedef short          s16x8 __attribute__((ext_vector_type(8)));
typedef unsigned short u16x8 __attribute__((ext_vector_type(8)));

static __device__ __forceinline__ unsigned short f2bf(float f) {
    unsigned int u = __float_as_uint(f);
    u += 0x7FFFu + ((u >> 16) & 1u);       // round-to-nearest-even
    return (unsigned short)(u >> 16);
}
// XOR swizzle for [row][256B] LDS tiles read 16B/lane (G4 pattern)
static __device__ __forceinline__ int swz(int local) {
    return local ^ (((local >> 8) & 7) << 4);
}

__global__ __launch_bounds__(256) void k_convert(const float* __restrict__ bw,
                                                 unsigned short* __restrict__ wbf) {
    int i = blockIdx.x * 256 + threadIdx.x;
    if (i < 128 * 128) wbf[i] = f2bf(bw[i]);
}

__global__ __launch_bounds__(256) void k_branch(
    const float* __restrict__ q, const float* __restrict__ k,
    const unsigned short* __restrict__ wbf,   // base_weight bf16 [d][e] (= B[n][k])
    const float* __restrict__ gridv,          // [12], == 1..12
    const float* __restrict__ coef_q, const float* __restrict__ coef_k,
    const float* __restrict__ sbase,          // scale_base (1,H,P,D)
    const float* __restrict__ ssp,            // scale_sp   (1,H,P,D)
    float* __restrict__ sums)
{
    __shared__ char smem[49152];
    char* A_l = smem;                 // [64 rows][128 k] bf16, swizzled
    char* W_l = smem + 16384;         // [128 n][128 k] bf16, swizzled
    float* F_l = (float*)smem;        // [64][132] f32 — reuses dead A/W after MFMA

    const int t = threadIdx.x;
    const int row0 = blockIdx.x * 64;
    const bool is_q = row0 < 32768;
    const float* X = is_q ? q : k;
    const float* coef = is_q ? coef_q : coef_k;
    const int xrow0 = is_q ? row0 : row0 - 32768;

    // ---- phase 1: stage W and silu(x) as bf16 ----
    #pragma unroll
    for (int it = 0; it < 8; ++it) {
        int c = it * 256 + t;
        u16x8 v = *(const u16x8*)&wbf[c * 8];
        *(u16x8*)(W_l + swz(c * 16)) = v;
    }
    #pragma unroll
    for (int it = 0; it < 4; ++it) {
        int c = it * 256 + t;                       // 0..1023
        int row = c >> 4, kc = c & 15;
        const float4* xp = (const float4*)&X[(xrow0 + row) * 128 + kc * 8];
        float4 x0 = xp[0], x1 = xp[1];
        float xs[8] = {x0.x, x0.y, x0.z, x0.w, x1.x, x1.y, x1.z, x1.w};
        u16x8 sv;
        #pragma unroll
        for (int j = 0; j < 8; ++j) {
            float s = xs[j] / (1.f + __expf(-xs[j]));   // silu
            sv[j] = f2bf(s);
        }
        *(u16x8*)(A_l + swz(c * 16)) = sv;
    }
    __syncthreads();

    // ---- phase 2: MFMA  out[m][n] = sum_k silu(x)[m][k] * W[n][k] ----
    const int l = t & 63, w = t >> 6;
    const int r15 = l & 15, g4 = l >> 4;

    f32x4 acc[8];
    #pragma unroll
    for (int n = 0; n < 8; ++n) acc[n] = (f32x4){0.f, 0.f, 0.f, 0.f};

    const int abase = (w * 16 + r15) * 256 + g4 * 16;   // A: row=m (wave's tile)
    const int bbase = r15 * 256 + g4 * 16;              // B: row=n
    #pragma unroll
    for (int s = 0; s < 4; ++s) {                       // k-steps of 32
        s16x8 af = *(const s16x8*)(A_l + swz(abase + s * 64));
        #pragma unroll
        for (int n = 0; n < 8; ++n) {
            s16x8 bf = *(const s16x8*)(W_l + swz(bbase + n * 16 * 256 + s * 64));
            acc[n] = __builtin_amdgcn_mfma_f32_16x16x32_bf16(af, bf, acc[n], 0, 0, 0);
        }
    }
    __syncthreads();   // all waves done reading A_l/W_l

    // ---- phase 3: dump acc into F_l[row][col] (C-frag: col=r15+n*16, row=g4*4+reg)
    #pragma unroll
    for (int n = 0; n < 8; ++n)
        #pragma unroll
        for (int reg = 0; reg < 4; ++reg)
            F_l[(w * 16 + g4 * 4 + reg) * 132 + n * 16 + r15] = acc[n][reg];
    __syncthreads();

    // ---- phase 4: epilogue in staging layout (all loads vectorized) ----
    const float g1 = gridv[0];   // == 1.0; basis freqs are g1*(1..12)

    #pragma unroll
    for (int it = 0; it < 4; ++it) {
        int c = it * 256 + t;
        int row = c >> 4, kc = c & 15;              // cols kc*8 .. kc*8+7
        int hp = (row0 + row) & 2047;
        const float4* Fp = (const float4*)&F_l[row * 132 + kc * 8];
        float4 F0 = Fp[0], F1 = Fp[1];
        const float4* xp = (const float4*)&X[(xrow0 + row) * 128 + kc * 8];
        float4 x0 = xp[0], x1 = xp[1];
        const float4* pp = (const float4*)&ssp[hp * 128 + kc * 8];
        float4 p0 = pp[0], p1 = pp[1];
        const float4* bp = (const float4*)&sbase[hp * 128 + kc * 8];
        float4 b0 = bp[0], b1 = bp[1];
        float Fv[8] = {F0.x, F0.y, F0.z, F0.w, F1.x, F1.y, F1.z, F1.w};
        float xs[8] = {x0.x, x0.y, x0.z, x0.w, x1.x, x1.y, x1.z, x1.w};
        float pv[8] = {p0.x, p0.y, p0.z, p0.w, p1.x, p1.y, p1.z, p1.w};
        float bv[8] = {b0.x, b0.y, b0.z, b0.w, b1.x, b1.y, b1.z, b1.w};
        float ps = 0.f;
        #pragma unroll
        for (int j = 0; j < 8; ++j) {
            int col = kc * 8 + j;
            const float4* cp = (const float4*)&coef[col * 12];
            float4 c0 = cp[0], c1 = cp[1], c2 = cp[2];
            float cf[12] = {c0.x, c0.y, c0.z, c0.w, c1.x, c1.y, c1.z, c1.w,
                            c2.x, c2.y, c2.z, c2.w};
            float a = g1 * xs[j];
            float s1, cv;
            __sincosf(a, &s1, &cv);
            float t2 = cv + cv;
            float sprev = 0.f, scur = s1;
            float f = cf[0] * s1;
            #pragma unroll
            for (int u = 1; u < 12; ++u) {
                float snext = __builtin_fmaf(t2, scur, -sprev);
                f = __builtin_fmaf(cf[u], snext, f);
                sprev = scur; scur = snext;
            }
            float z = f * pv[j] + Fv[j] * bv[j];
            ps += 1.f / (1.f + __expf(-z));
        }
        // reduce over the 16 lanes sharing this row (kc = lane&15)
        ps += __shfl_xor(ps, 1, 64);
        ps += __shfl_xor(ps, 2, 64);
        ps += __shfl_xor(ps, 4, 64);
        ps += __shfl_xor(ps, 8, 64);
        if (kc == 0) sums[row0 + row] = ps;
    }
}

// T[bh][j] = sum_p sk[bh][p]*w_qk[j][p] + b_qk[j]; block 256 computes R[j].
__global__ __launch_bounds__(128) void k_tvec(
    const float* __restrict__ sums, const float* __restrict__ w_qk,
    const float* __restrict__ b_qk, float* __restrict__ T, float* __restrict__ R)
{
    __shared__ float skl[128];
    int bh = blockIdx.x;
    int t = threadIdx.x;
    const float4* wr = (const float4*)&w_qk[t * 128];
    if (bh < 256) {
        skl[t] = sums[32768 + bh * 128 + t];
        __syncthreads();
        float a = 0.f;
        #pragma unroll 8
        for (int p4 = 0; p4 < 32; ++p4) {
            float4 w4 = wr[p4];
            a += w4.x * skl[p4 * 4 + 0] + w4.y * skl[p4 * 4 + 1] +
                 w4.z * skl[p4 * 4 + 2] + w4.w * skl[p4 * 4 + 3];
        }
        T[bh * 128 + t] = a + b_qk[t];
    } else {
        float a = 0.f;
        #pragma unroll 8
        for (int p4 = 0; p4 < 32; ++p4) {
            float4 w4 = wr[p4];
            a += w4.x + w4.y + w4.z + w4.w;
        }
        R[t] = a;
    }
}

// Softmax over j: logit[j] = sq[row]*R[j] + T[bh][j]. One wave per row.
__global__ __launch_bounds__(256) void k_softmax(
    const float* __restrict__ sums, const float* __restrict__ T,
    const float* __restrict__ R, float* __restrict__ out)
{
    int row = blockIdx.x * 4 + (threadIdx.x >> 6);
    int lane = threadIdx.x & 63;
    int bh = row >> 7;
    float sqv = sums[row];
    int j0 = lane, j1 = lane + 64;
    float l0 = sqv * R[j0] + T[bh * 128 + j0];
    float l1 = sqv * R[j1] + T[bh * 128 + j1];
    float m = fmaxf(l0, l1);
    #pragma unroll
    for (int s = 32; s >= 1; s >>= 1) m = fmaxf(m, __shfl_xor(m, s, 64));
    float e0 = __expf(l0 - m), e1 = __expf(l1 - m);
    float sum = e0 + e1;
    #pragma unroll
    for (int w2 = 32; w2 >= 1; w2 >>= 1) sum += __shfl_xor(sum, w2, 64);
    float inv = 1.f / sum;
    out[row * 128 + j0] = e0 * inv;
    out[row * 128 + j1] = e1 * inv;
}

extern "C" void kernel_launch(void* const* d_in, const int* in_sizes, int n_in,
                              void* d_out, int out_size, void* d_ws, size_t ws_size,
                              hipStream_t stream) {
    (void)in_sizes; (void)n_in; (void)out_size; (void)ws_size;
    const float* q      = (const float*)d_in[0];
    const float* k      = (const float*)d_in[1];
    // d_in[2] = scale (unused by reference forward)
    const float* gridv  = (const float*)d_in[3];
    const float* bw     = (const float*)d_in[4];
    const float* coef_q = (const float*)d_in[5];
    const float* coef_k = (const float*)d_in[6];
    const float* sbase  = (const float*)d_in[7];   // scale_base
    const float* ssp    = (const float*)d_in[8];   // scale_sp
    const float* w_qk   = (const float*)d_in[9];
    const float* b_qk   = (const float*)d_in[10];

    float* out  = (float*)d_out;
    float* ws   = (float*)d_ws;
    float* sums = ws;                               // 65536
    float* R    = ws + 65536;                       // 128
    float* T    = ws + 65664;                       // 32768
    unsigned short* wbf = (unsigned short*)(ws + 98432);  // 16384 ushorts

    k_convert<<<64, 256, 0, stream>>>(bw, wbf);
    k_branch<<<1024, 256, 0, stream>>>(q, k, wbf, gridv, coef_q, coef_k,
                                       sbase, ssp, sums);
    k_tvec<<<257, 128, 0, stream>>>(sums, w_qk, b_qk, T, R);
    k_softmax<<<32768 / 4, 256, 0, stream>>>(sums, T, R, out);
}